// Round 13
// baseline (2030.269 us; speedup 1.0000x reference)
//
#include <hip/hip_runtime.h>
#include <math.h>
#include <stdint.h>

#define SS 2048
#define II 32
#define TB 2

typedef _Float16 f16x8  __attribute__((ext_vector_type(8)));
typedef float    f32x4  __attribute__((ext_vector_type(4)));
typedef uint32_t u32x4e __attribute__((ext_vector_type(4)));
typedef _Float16 f16x2  __attribute__((ext_vector_type(2)));
typedef __fp16   g16x2  __attribute__((ext_vector_type(2)));

union uhc { uint32_t u; f16x2 a; g16x2 b; };
union frag { f16x8 v; uint32_t w[4]; u32x4e q; };

__device__ __forceinline__ uint32_t pk(float x, float y) {
    uhc c; c.b = __builtin_amdgcn_cvt_pkrtz(x, y); return c.u;
}
__device__ __forceinline__ float fdot2(uint32_t a, uint32_t b, float c) {
    uhc x, y; x.u = a; y.u = b;
#if __has_builtin(__builtin_amdgcn_fdot2)
    return __builtin_amdgcn_fdot2(x.a, y.a, c, false);
#else
    return c + (float)x.a.x * (float)y.a.x + (float)x.a.y * (float)y.a.y;
#endif
}
__device__ __forceinline__ float sigm(float x) { return __builtin_amdgcn_rcpf(1.f + __expf(-x)); }
__device__ __forceinline__ float tanh_(float x) {
    x = fminf(fmaxf(x, -15.f), 15.f);
    float e = __expf(-2.f * x);
    return (1.f - e) * __builtin_amdgcn_rcpf(1.f + e);
}
__device__ __forceinline__ frag load8(const float* p) {
    float4 v0 = ((const float4*)p)[0];
    float4 v1 = ((const float4*)p)[1];
    frag f;
    f.w[0] = pk(v0.x, v0.y); f.w[1] = pk(v0.z, v0.w);
    f.w[2] = pk(v1.x, v1.y); f.w[3] = pk(v1.z, v1.w);
    return f;
}
#define MFMA(A, B, C) __builtin_amdgcn_mfma_f32_16x16x32_f16((A).v, (B).v, (C), 0, 0, 0)
// component select (j&3) then k-half select (j>>2)
#define EXTR1(A) (jhi ? (jlo ? (A)[3] : (A)[2]) : (jlo ? (A)[1] : (A)[0]))
#define EXTR(A0, A1) (khi ? EXTR1(A1) : EXTR1(A0))

__global__ __launch_bounds__(256, 1) void lstm_mfma(
    const float* __restrict__ x,
    const float* __restrict__ h_in, const float* __restrict__ c_in,
    const float* __restrict__ Wih0, const float* __restrict__ Whh0,
    const float* __restrict__ bih0, const float* __restrict__ bhh0,
    const float* __restrict__ Wih1, const float* __restrict__ Whh1,
    const float* __restrict__ bih1, const float* __restrict__ bhh1,
    const float* __restrict__ Wh, const float* __restrict__ bh,
    float* __restrict__ out)
{
    // hbuf[parity][layer]: packed f16 h; slot (kgroup*2+bb) of 16B; kgroup = unit>>3
    __shared__ uint32_t hbuf[2][2][64];
    __shared__ uint32_t xsb[2][16][32];     // [chunk parity][step][(g*2+bb)*4 words]
    __shared__ float    pbuf[64][2];        // probs ring [t&63][batch]

    const int tid = threadIdx.x;
    const int w   = tid >> 6, L = tid & 63;
    const int q   = w & 1;                  // wave within layer group
    const int isL1 = (w >= 2);
    const int g16 = L >> 4, b16 = L & 15;
    const int bb  = b16 & 1, j = b16 >> 1;
    const int u   = 32 * q + 16 * (j >> 2) + 4 * g16 + (j & 3);   // lane's owned unit
    const int bbase = blockIdx.x * TB;
    const int loff  = isL1 ? 16384 : 0;
    const bool jlo = (j & 1) != 0, jhi = (j & 2) != 0, khi = (j & 4) != 0;
    const int hoff = ((u >> 3) * 2 + bb) * 16 + (u & 7) * 2;      // lane's own f16 slot

    const f32x4 zf4 = {0.f, 0.f, 0.f, 0.f};

    // ---- initial state: lane owns cell (u, bb) of its layer ----
    float hst = h_in[loff + (size_t)(bbase + bb) * 64 + u];
    float cst = c_in[loff + (size_t)(bbase + bb) * 64 + u];
    *(__fp16*)((char*)&hbuf[1][isL1][0] + hoff) = (__fp16)hst;    // h(-1)

    // per-lane gate biases (row = t*64 + u)
    float bias0 = bih0[u] + bhh0[u], bias1, bias2, bias3;
    if (isL1) {
        bias0 = bih1[u] + bhh1[u];
        bias1 = bih1[64 + u] + bhh1[64 + u];
        bias2 = bih1[128 + u] + bhh1[128 + u];
        bias3 = bih1[192 + u] + bhh1[192 + u];
    } else {
        bias1 = bih0[64 + u] + bhh0[64 + u];
        bias2 = bih0[128 + u] + bhh0[128 + u];
        bias3 = bih0[192 + u] + bhh0[192 + u];
    }

    // x staging geometry (threads 0..127, i.e. the two L0 waves)
    const int s_ = tid >> 3, g_ = (tid >> 1) & 3, bb_ = tid & 1;
    const float* xsrc_base = x + (size_t)(bbase + bb_) * (SS * II) + (size_t)s_ * II + g_ * 8;

    // ---- stage chunk 0 synchronously (prologue only) ----
    if (tid < 128) {
        float4 v0_ = ((const float4*)xsrc_base)[0];
        float4 v1_ = ((const float4*)xsrc_base)[1];
        u32x4e wv_ = { pk(v0_.x, v0_.y), pk(v0_.z, v0_.w), pk(v1_.x, v1_.y), pk(v1_.z, v1_.w) };
        *(u32x4e*)((char*)&xsb[0][s_][0] + (g_ * 2 + bb_) * 16) = wv_;
    }
    __syncthreads();

    if (!isL1) {
        // ========== L0 waves: 8 M-tiles (4 gates x 2 unit-halves); w0 also runs the head ==========
        frag aH[4][2][2], aX[4][2];
        #pragma unroll
        for (int t = 0; t < 4; ++t) {
            #pragma unroll
            for (int k = 0; k < 2; ++k) {
                const int arow = t * 64 + 32 * q + 16 * k + b16;
                aH[t][k][0] = load8(Whh0 + arow * 64 + g16 * 8);
                aH[t][k][1] = load8(Whh0 + arow * 64 + 32 + g16 * 8);
                aX[t][k]    = load8(Wih0 + arow * 32 + g16 * 8);
            }
        }
        // head constants (used by wave 0)
        frag whA = load8(Wh + g16 * 8);
        frag whB = load8(Wh + 32 + g16 * 8);
        const float bhs = bh[0];
        float4 xr0, xr1;

        #pragma unroll 2
        for (int it = 0; it <= SS + 1; ++it) {
            if ((it & 15) == 0 && it + 16 < SS && tid < 128) {   // T14: issue loads early
                const float* p_ = xsrc_base + (size_t)(((it >> 4) + 1) * 16) * II;
                xr0 = ((const float4*)p_)[0];
                xr1 = ((const float4*)p_)[1];
            }
            if (it < SS) {
                const char* hb = (const char*)&hbuf[(it + 1) & 1][0][0];   // h0(it-1)
                frag bh0, bh1, bx;
                bh0.v = *(const f16x8*)(hb + (g16 * 2 + bb) * 16);
                bh1.v = *(const f16x8*)(hb + ((4 + g16) * 2 + bb) * 16);
                bx.v  = *(const f16x8*)((const char*)&xsb[(it >> 4) & 1][it & 15][0]
                                        + (g16 * 2 + bb) * 16);
                f32x4 acc[4][2];
                #pragma unroll
                for (int t = 0; t < 4; ++t) {
                    #pragma unroll
                    for (int k = 0; k < 2; ++k) {
                        f32x4 p = MFMA(aH[t][k][0], bh0, zf4);
                        p = MFMA(aX[t][k], bx, p);
                        f32x4 qq = MFMA(aH[t][k][1], bh1, zf4);
                        acc[t][k] = p + qq;
                    }
                }
                float gi = sigm(EXTR(acc[0][0], acc[0][1]) + bias0);
                float gf = sigm(EXTR(acc[1][0], acc[1][1]) + bias1);
                float gg = tanh_(EXTR(acc[2][0], acc[2][1]) + bias2);
                float go = sigm(EXTR(acc[3][0], acc[3][1]) + bias3);
                cst = gf * cst + gi * gg;
                hst = go * tanh_(cst);
                *(__fp16*)((char*)&hbuf[it & 1][0][0] + hoff) = (__fp16)hst;   // h0(it)
            }
            if (w == 0 && it >= 2) {
                // head for step t = it-2 from h1(it-2)
                const char* h1b = (const char*)&hbuf[it & 1][1][0];
                frag b1, b1k;
                b1.v  = *(const f16x8*)(h1b + (g16 * 2 + bb) * 16);
                b1k.v = *(const f16x8*)(h1b + ((4 + g16) * 2 + bb) * 16);
                float pv = 0.f;
                #pragma unroll
                for (int i = 0; i < 4; ++i) {
                    pv = fdot2(whA.w[i], b1.w[i], pv);
                    pv = fdot2(whB.w[i], b1k.w[i], pv);
                }
                // reduce over the 4 g16 k-slices ONLY (lane bits 4,5);
                // j-variant lanes (bits 1-3) hold duplicate partials - do NOT sum them.
                pv += __shfl_xor(pv, 16);
                pv += __shfl_xor(pv, 32);
                pv = sigm(pv + bhs);
                const int t = it - 2;
                if (L < 2) pbuf[t & 63][L] = pv;
                if ((t & 63) == 63) {
                    const int tbase = t & ~63;
                    const int fb = L >> 4, fs = (L & 15) * 4;
                    if (L < 32) {
                        float4 vv = make_float4(pbuf[fs][fb], pbuf[fs + 1][fb],
                                                pbuf[fs + 2][fb], pbuf[fs + 3][fb]);
                        *(float4*)(out + (size_t)(bbase + fb) * SS + tbase + fs) = vv;
                    }
                }
            }
            if ((it & 15) == 8 && it + 8 < SS && tid < 128) {    // T14: write staged chunk late
                const int cn = (it >> 4) + 1;
                u32x4e wv_ = { pk(xr0.x, xr0.y), pk(xr0.z, xr0.w),
                               pk(xr1.x, xr1.y), pk(xr1.z, xr1.w) };
                *(u32x4e*)((char*)&xsb[cn & 1][s_][0] + (g_ * 2 + bb_) * 16) = wv_;
            }
            __syncthreads();
        }
    } else {
        // ========== L1 waves (1-step skew): at iter it compute step it-1 ==========
        frag aI[4][2][2], aR[4][2][2];
        #pragma unroll
        for (int t = 0; t < 4; ++t) {
            #pragma unroll
            for (int k = 0; k < 2; ++k) {
                const int arow = t * 64 + 32 * q + 16 * k + b16;
                aI[t][k][0] = load8(Wih1 + arow * 64 + g16 * 8);
                aI[t][k][1] = load8(Wih1 + arow * 64 + 32 + g16 * 8);
                aR[t][k][0] = load8(Whh1 + arow * 64 + g16 * 8);
                aR[t][k][1] = load8(Whh1 + arow * 64 + 32 + g16 * 8);
            }
        }

        #pragma unroll 2
        for (int it = 0; it <= SS + 1; ++it) {
            if (it >= 1 && it <= SS) {
                const char* h1b = (const char*)&hbuf[it & 1][1][0];        // h1(it-2)
                const char* h0b = (const char*)&hbuf[(it + 1) & 1][0][0];  // h0(it-1)
                frag b0, b0k, b1, b1k;
                b0.v  = *(const f16x8*)(h0b + (g16 * 2 + bb) * 16);
                b0k.v = *(const f16x8*)(h0b + ((4 + g16) * 2 + bb) * 16);
                b1.v  = *(const f16x8*)(h1b + (g16 * 2 + bb) * 16);
                b1k.v = *(const f16x8*)(h1b + ((4 + g16) * 2 + bb) * 16);
                f32x4 acc[4][2];
                #pragma unroll
                for (int t = 0; t < 4; ++t) {
                    #pragma unroll
                    for (int k = 0; k < 2; ++k) {
                        f32x4 p = MFMA(aI[t][k][0], b0, zf4);
                        p = MFMA(aR[t][k][0], b1, p);
                        f32x4 qq = MFMA(aI[t][k][1], b0k, zf4);
                        qq = MFMA(aR[t][k][1], b1k, qq);
                        acc[t][k] = p + qq;
                    }
                }
                float gi = sigm(EXTR(acc[0][0], acc[0][1]) + bias0);
                float gf = sigm(EXTR(acc[1][0], acc[1][1]) + bias1);
                float gg = tanh_(EXTR(acc[2][0], acc[2][1]) + bias2);
                float go = sigm(EXTR(acc[3][0], acc[3][1]) + bias3);
                cst = gf * cst + gi * gg;
                hst = go * tanh_(cst);
                *(__fp16*)((char*)&hbuf[(it + 1) & 1][1][0] + hoff) = (__fp16)hst;  // h1(it-1)
            }
            __syncthreads();
        }
    }

    // ---- final states: h at 524288 (2,256,64), c at 557056 ----
    out[524288 + loff + (size_t)(bbase + bb) * 64 + u] = hst;
    out[557056 + loff + (size_t)(bbase + bb) * 64 + u] = cst;
}

extern "C" void kernel_launch(void* const* d_in, const int* in_sizes, int n_in,
                              void* d_out, int out_size, void* d_ws, size_t ws_size,
                              hipStream_t stream) {
    const float* x    = (const float*)d_in[0];
    const float* h0   = (const float*)d_in[1];
    const float* c0   = (const float*)d_in[2];
    const float* Wih0 = (const float*)d_in[3];
    const float* Whh0 = (const float*)d_in[4];
    const float* bih0 = (const float*)d_in[5];
    const float* bhh0 = (const float*)d_in[6];
    const float* Wih1 = (const float*)d_in[7];
    const float* Whh1 = (const float*)d_in[8];
    const float* bih1 = (const float*)d_in[9];
    const float* bhh1 = (const float*)d_in[10];
    const float* Wh   = (const float*)d_in[11];
    const float* bh   = (const float*)d_in[12];
    float* out = (float*)d_out;

    hipLaunchKernelGGL(lstm_mfma, dim3(256 / TB), dim3(256), 0, stream,
                       x, h0, c0, Wih0, Whh0, bih0, bhh0,
                       Wih1, Whh1, bih1, bhh1, Wh, bh, out);
}